// Round 1
// baseline (626.035 us; speedup 1.0000x reference)
//
#include <hip/hip_runtime.h>

// Problem constants (static shapes from setup_inputs / reference)
#define BN   16          // batch
#define TN   60000       // frames
#define FN   80          // features
#define NF4  20          // FN/4 float4 groups
#define SEG  100         // segment / chunk length (frames)
#define NSEG 600         // TN/SEG
#define WIN  600         // CMN_WINDOW
#define SBK  6           // WIN/SEG segments back

// Workspace layout: ck[b][seg][f4][8] floats = {sum.xyzw, sumsq.xyzw}
// size = 16*600*20*8*4 B = 6.144 MB

__global__ __launch_bounds__(256) void k_segsum(const float* __restrict__ x,
                                                float* __restrict__ ck) {
    int tid = blockIdx.x * 256 + threadIdx.x;
    if (tid >= BN * NSEG * NF4) return;
    int f4   = tid % NF4;
    int seg  = (tid / NF4) % NSEG;
    int b    = tid / (NF4 * NSEG);
    const float* p = x + ((size_t)b * TN + (size_t)seg * SEG) * FN + f4 * 4;
    float s0=0.f,s1=0.f,s2=0.f,s3=0.f,q0=0.f,q1=0.f,q2=0.f,q3=0.f;
    for (int i = 0; i < SEG; ++i) {
        float4 v = *reinterpret_cast<const float4*>(p + (size_t)i * FN);
        s0 += v.x; s1 += v.y; s2 += v.z; s3 += v.w;
        q0 += v.x*v.x; q1 += v.y*v.y; q2 += v.z*v.z; q3 += v.w*v.w;
    }
    float* o = ck + (size_t)tid * 8;   // tid ordering (b,seg,f4) == ck layout
    o[0]=s0; o[1]=s1; o[2]=s2; o[3]=s3;
    o[4]=q0; o[5]=q1; o[6]=q2; o[7]=q3;
}

// In-place exclusive scan over the seg axis, one thread per (b, f4, component)
__global__ __launch_bounds__(256) void k_scan(float* __restrict__ ck) {
    int tid = blockIdx.x * 256 + threadIdx.x;
    if (tid >= BN * NF4 * 8) return;   // 2560
    int comp = tid % 8;
    int f4   = (tid / 8) % NF4;
    int b    = tid / (8 * NF4);
    float* p = ck + (((size_t)b * NSEG) * NF4 + f4) * 8 + comp;
    float run = 0.f;
    const size_t stride = (size_t)NF4 * 8;  // 160 floats between segs
    for (int k = 0; k < NSEG; ++k) {
        float v = p[(size_t)k * stride];
        p[(size_t)k * stride] = run;
        run += v;
    }
}

__global__ __launch_bounds__(256) void k_out(const float* __restrict__ x,
                                             const float* __restrict__ ck,
                                             float* __restrict__ out) {
    int tid = blockIdx.x * 256 + threadIdx.x;
    if (tid >= BN * NSEG * NF4) return;
    int f4    = tid % NF4;
    int chunk = (tid / NF4) % NSEG;
    int b     = tid / (NF4 * NSEG);
    size_t base = ((size_t)b * TN + (size_t)chunk * SEG) * FN + f4 * 4;
    const float* xl = x + base;
    float* o = out + base;
    const float* ckL = ck + (size_t)tid * 8;

    if (chunk == 0) {
        // t in [0,99]: window fixed [0,100) -> stats = cs[100] = ck[b][1]
        const float* c1 = ck + (((size_t)(b * NSEG + 1)) * NF4 + f4) * 8;
        const float rn = 1.0f / 100.0f;
        float m0=c1[0]*rn, m1=c1[1]*rn, m2=c1[2]*rn, m3=c1[3]*rn;
        float i0=rsqrtf(c1[4]*rn - m0*m0);
        float i1=rsqrtf(c1[5]*rn - m1*m1);
        float i2=rsqrtf(c1[6]*rn - m2*m2);
        float i3=rsqrtf(c1[7]*rn - m3*m3);
        for (int i = 0; i < SEG; ++i) {
            float4 v = *reinterpret_cast<const float4*>(xl + (size_t)i * FN);
            float4 r;
            r.x = (v.x - m0) * i0; r.y = (v.y - m1) * i1;
            r.z = (v.z - m2) * i2; r.w = (v.w - m3) * i3;
            *reinterpret_cast<float4*>(o + (size_t)i * FN) = r;
        }
    } else if (chunk < SBK) {
        // t in [100,599]: window [0, t+1), growing n
        float ls0=ckL[0], ls1=ckL[1], ls2=ckL[2], ls3=ckL[3];
        float lq0=ckL[4], lq1=ckL[5], lq2=ckL[6], lq3=ckL[7];
        for (int i = 0; i < SEG; ++i) {
            float4 v = *reinterpret_cast<const float4*>(xl + (size_t)i * FN);
            ls0 += v.x; ls1 += v.y; ls2 += v.z; ls3 += v.w;
            lq0 += v.x*v.x; lq1 += v.y*v.y; lq2 += v.z*v.z; lq3 += v.w*v.w;
            float rn = 1.0f / (float)(chunk * SEG + i + 1);
            float m0=ls0*rn, m1=ls1*rn, m2=ls2*rn, m3=ls3*rn;
            float4 r;
            r.x = (v.x - m0) * rsqrtf(lq0*rn - m0*m0);
            r.y = (v.y - m1) * rsqrtf(lq1*rn - m1*m1);
            r.z = (v.z - m2) * rsqrtf(lq2*rn - m2*m2);
            r.w = (v.w - m3) * rsqrtf(lq3*rn - m3*m3);
            *reinterpret_cast<float4*>(o + (size_t)i * FN) = r;
        }
    } else {
        // t >= 600: window [t-600, t+1), n = 601
        float ls0=ckL[0], ls1=ckL[1], ls2=ckL[2], ls3=ckL[3];
        float lq0=ckL[4], lq1=ckL[5], lq2=ckL[6], lq3=ckL[7];
        const float* ckT = ck + (((size_t)(b * NSEG + chunk - SBK)) * NF4 + f4) * 8;
        float ts0=ckT[0], ts1=ckT[1], ts2=ckT[2], ts3=ckT[3];
        float tq0=ckT[4], tq1=ckT[5], tq2=ckT[6], tq3=ckT[7];
        const float* xt = xl - (size_t)WIN * FN;
        const float rn = 1.0f / 601.0f;
        for (int i = 0; i < SEG; ++i) {
            float4 v = *reinterpret_cast<const float4*>(xl + (size_t)i * FN);
            float4 w = *reinterpret_cast<const float4*>(xt + (size_t)i * FN);
            ls0 += v.x; ls1 += v.y; ls2 += v.z; ls3 += v.w;
            lq0 += v.x*v.x; lq1 += v.y*v.y; lq2 += v.z*v.z; lq3 += v.w*v.w;
            float s0 = ls0 - ts0, s1 = ls1 - ts1, s2 = ls2 - ts2, s3 = ls3 - ts3;
            float q0 = lq0 - tq0, q1 = lq1 - tq1, q2 = lq2 - tq2, q3 = lq3 - tq3;
            float m0 = s0*rn, m1 = s1*rn, m2 = s2*rn, m3 = s3*rn;
            float4 r;
            r.x = (v.x - m0) * rsqrtf(q0*rn - m0*m0);
            r.y = (v.y - m1) * rsqrtf(q1*rn - m1*m1);
            r.z = (v.z - m2) * rsqrtf(q2*rn - m2*m2);
            r.w = (v.w - m3) * rsqrtf(q3*rn - m3*m3);
            *reinterpret_cast<float4*>(o + (size_t)i * FN) = r;
            ts0 += w.x; ts1 += w.y; ts2 += w.z; ts3 += w.w;
            tq0 += w.x*w.x; tq1 += w.y*w.y; tq2 += w.z*w.z; tq3 += w.w*w.w;
        }
    }
}

extern "C" void kernel_launch(void* const* d_in, const int* in_sizes, int n_in,
                              void* d_out, int out_size, void* d_ws, size_t ws_size,
                              hipStream_t stream) {
    const float* x = (const float*)d_in[0];
    float* out = (float*)d_out;
    float* ck = (float*)d_ws;   // needs 6.144 MB

    const int n1 = BN * NSEG * NF4;          // 192000 threads
    k_segsum<<<(n1 + 255) / 256, 256, 0, stream>>>(x, ck);
    k_scan<<<(BN * NF4 * 8 + 255) / 256, 256, 0, stream>>>(ck);
    k_out<<<(n1 + 255) / 256, 256, 0, stream>>>(x, ck, out);
}